// Round 2
// baseline (568.857 us; speedup 1.0000x reference)
//
#include <hip/hip_runtime.h>
#include <math.h>

// Analytic collapse of the reference (verified, absmax 3.9e-3):
//   t = tanh(W1 @ x_n); v = tanh(W2 @ t); z = Wout . v
//   a = sum_h sob[h] * sin(2*pi*soa[h]*z/7)
//   out = sign(a) * 4*z*e^{|a|} / (4*e^{|a|} + 5),  0 if a == 0
//
// Structure: lane = row, broadcast weights.
//   block = 256 threads = 4 waves; 64 rows/block; wave w owns outputs [32w,32w+32)
//   inner step: 1 per-lane x read (b128, swizzled) + 32 uniform-address
//   (broadcast) weight b128 reads -> 128 FMAs  =>  ~0.09 B LDS per FLOP.

#define NROWS 65536
#define ROWS  64

__global__ __launch_bounds__(256, 2)
void fused_mlp2(const float* __restrict__ x,
                const float* __restrict__ W1,
                const float* __restrict__ W2,
                const float* __restrict__ Wout,
                const float* __restrict__ soa,
                const float* __restrict__ sob,
                float* __restrict__ out)
{
    __shared__ float4 xs[1024];   // 16 KB: x chunk [64 rows][16 f4], slot s = src ^ (row&15)
    __shared__ float4 ws[2048];   // 32 KB: weight chunk [128 o][16 f4], linear
    __shared__ float4 ts[2048];   // 32 KB: t tile [64 rows][32 f4], slot = s ^ (row&31)
    float* zpart = reinterpret_cast<float*>(xs);   // [4][64], aliases xs (dead after L1)

    const int tid  = threadIdx.x;
    const int wv   = tid >> 6;
    const int lane = tid & 63;         // lane = row within block
    const int o0   = wv << 5;          // this wave's 32 outputs
    const int n0   = blockIdx.x * ROWS;

    const float4* xg  = reinterpret_cast<const float4*>(x);    // [N][64]
    const float4* w1g = reinterpret_cast<const float4*>(W1);   // [128][64]
    const float4* w2g = reinterpret_cast<const float4*>(W2);   // [128][32]

    float acc[32];
    #pragma unroll
    for (int j = 0; j < 32; ++j) acc[j] = 0.f;

    // ---------------- layer 1: K=256, 4 chunks of 64 ----------------
    for (int c = 0; c < 4; ++c) {
        __syncthreads();
        #pragma unroll
        for (int i = 0; i < 4; ++i) {              // stage x chunk (swizzled slot)
            int idx = tid + i * 256;               // 0..1023
            int row = idx >> 4, s = idx & 15;
            xs[idx] = xg[(size_t)(n0 + row) * 64 + c * 16 + (s ^ (row & 15))];
        }
        #pragma unroll
        for (int i = 0; i < 8; ++i) {              // stage W1 chunk (linear)
            int idx = tid + i * 256;               // 0..2047
            int o = idx >> 4, s = idx & 15;
            ws[idx] = w1g[o * 64 + c * 16 + s];
        }
        __syncthreads();
        #pragma unroll
        for (int s4 = 0; s4 < 16; ++s4) {
            float4 xv = xs[(lane << 4) + (s4 ^ (lane & 15))];
            #pragma unroll
            for (int j = 0; j < 32; ++j) {
                float4 wvv = ws[((o0 + j) << 4) + s4];   // uniform addr -> broadcast
                acc[j] += xv.x*wvv.x + xv.y*wvv.y + xv.z*wvv.z + xv.w*wvv.w;
            }
        }
    }

    // ---- epilogue 1: t = tanh(acc) -> ts (swizzled), reset acc ----
    #pragma unroll
    for (int jj = 0; jj < 8; ++jj) {
        float4 tv;
        tv.x = tanhf(acc[4*jj+0]);
        tv.y = tanhf(acc[4*jj+1]);
        tv.z = tanhf(acc[4*jj+2]);
        tv.w = tanhf(acc[4*jj+3]);
        int s = (wv << 3) + jj;                    // global f4-slot 0..31
        ts[(lane << 5) + (s ^ (lane & 31))] = tv;
        acc[4*jj+0] = acc[4*jj+1] = acc[4*jj+2] = acc[4*jj+3] = 0.f;
    }
    __syncthreads();

    // ---------------- layer 2: K=128, 2 chunks of 64 ----------------
    for (int c = 0; c < 2; ++c) {
        if (c) __syncthreads();                    // protect ws overwrite
        #pragma unroll
        for (int i = 0; i < 8; ++i) {
            int idx = tid + i * 256;
            int o = idx >> 4, s = idx & 15;
            ws[idx] = w2g[o * 32 + c * 16 + s];
        }
        __syncthreads();
        #pragma unroll
        for (int s4 = 0; s4 < 16; ++s4) {
            int fg = c * 16 + s4;                  // global f4 index 0..31
            float4 tv = ts[(lane << 5) + (fg ^ (lane & 31))];
            #pragma unroll
            for (int j = 0; j < 32; ++j) {
                float4 wvv = ws[((o0 + j) << 4) + s4];
                acc[j] += tv.x*wvv.x + tv.y*wvv.y + tv.z*wvv.z + tv.w*wvv.w;
            }
        }
    }

    // ---- epilogue 2: v = tanh(acc); partial z = v . Wout[o0:o0+32] ----
    float zp = 0.f;
    #pragma unroll
    for (int j = 0; j < 32; ++j)
        zp += tanhf(acc[j]) * Wout[o0 + j];        // Wout read is wave-uniform

    zpart[(wv << 6) + lane] = zp;                  // aliases xs (dead)
    __syncthreads();

    // ---- final: z -> analytic path collapse ----
    if (wv == 0) {
        float z = zpart[lane] + zpart[64 + lane] + zpart[128 + lane] + zpart[192 + lane];
        const float CC = 0.8975979010256552f;      // 2*pi/7
        float a = 0.f;
        #pragma unroll
        for (int h = 0; h < 32; ++h)
            a += sob[h] * sinf(CC * soa[h] * z);   // soa/sob uniform -> s_load
        float m   = expf(fabsf(a));
        float res = 4.f * z * m / (4.f * m + 5.f);
        out[n0 + lane] = (a > 0.f) ? res : ((a < 0.f) ? -res : 0.f);
    }
}

extern "C" void kernel_launch(void* const* d_in, const int* in_sizes, int n_in,
                              void* d_out, int out_size, void* d_ws, size_t ws_size,
                              hipStream_t stream) {
    const float* x    = (const float*)d_in[0];
    const float* W1   = (const float*)d_in[1];
    const float* W2   = (const float*)d_in[2];
    const float* Wout = (const float*)d_in[3];
    const float* soa  = (const float*)d_in[8];
    const float* sob  = (const float*)d_in[9];
    float* outp = (float*)d_out;

    dim3 grid(NROWS / ROWS);   // 1024
    dim3 block(256);
    hipLaunchKernelGGL(fused_mlp2, grid, block, 0, stream,
                       x, W1, W2, Wout, soa, sob, outp);
}

// Round 3
// 330.326 us; speedup vs baseline: 1.7221x; 1.7221x over previous
//
#include <hip/hip_runtime.h>
#include <math.h>

// Analytic collapse of the reference (verified rounds 1-2, absmax 3.9e-3):
//   t = tanh(W1 @ x_n); v = tanh(W2 @ t); z = Wout . v
//   a = sum_h sob[h] * sin(2*pi*soa[h]*z/7)
//   out = sign(a) * 4*z*e^{|a|} / (4*e^{|a|} + 5),  0 if a == 0
//
// Structure (R3): lane = row; weights via wave-uniform scalar loads (SGPR
// operand of v_fma) so the LDS pipe only carries x/t at 256 FMA per ds_read.
//   block = 256 thr = 4 waves = 2 rowgroups x 2 out-halves; 128 rows/block.
//   acc[64] per lane, fully unrolled (static reg indices).
//   x: global -> reg (prefetch next chunk) -> per-wave LDS -> own-row ds_read.
//   t exchanged between out-half waves via 64 KB swizzled ts tile.

#define NROWS 65536

__global__ __launch_bounds__(256, 2)
void fused_mlp3(const float* __restrict__ x,
                const float* __restrict__ W1,
                const float* __restrict__ W2,
                const float* __restrict__ Wout,
                const float* __restrict__ soa,
                const float* __restrict__ sob,
                float* __restrict__ out)
{
    __shared__ float4 ts[128 * 32];    // 64 KB: t[row][o-slot], slot ^= (row&7)
    __shared__ float4 xbuf[4][256];    // 16 KB: per-wave [64 rows][4 f4], q ^= (row&3)

    const int tid  = threadIdx.x;
    const int lane = tid & 63;
    const int w    = __builtin_amdgcn_readfirstlane(tid >> 6);  // force uniform
    const int g    = w >> 1;           // row group (0/1)
    const int h    = w & 1;            // output half (0/1)
    const int obase = h * 64;
    const int lrow  = g * 64 + lane;   // local row 0..127
    const int rowbase = blockIdx.x * 128 + g * 64;

    const float4* xg = reinterpret_cast<const float4*>(x);   // [N][64]
    float4* xb = xbuf[w];

    float acc[64];
    #pragma unroll
    for (int j = 0; j < 64; ++j) acc[j] = 0.f;

    // ---- prologue: stage k-chunk 0 (16 floats x 64 rows, coalesced 64B/row) ----
    #pragma unroll
    for (int i = 0; i < 4; ++i) {
        int idx = lane + 64 * i;               // 0..255
        int row = idx >> 2, q = idx & 3;
        xb[(row << 2) + (q ^ (row & 3))] = xg[(size_t)(rowbase + row) * 64 + q];
    }

    // ---------------- layer 1: K=256, 16 chunks of 16 floats ----------------
    #pragma unroll 1
    for (int kc = 0; kc < 16; ++kc) {
        // own row's 16 floats (4 swizzled b128 reads)
        float4 x0 = xb[(lane << 2) + (0 ^ (lane & 3))];
        float4 x1 = xb[(lane << 2) + (1 ^ (lane & 3))];
        float4 x2 = xb[(lane << 2) + (2 ^ (lane & 3))];
        float4 x3 = xb[(lane << 2) + (3 ^ (lane & 3))];

        // issue next chunk's global loads now; latency hides under the FMA body
        int kcn = kc + 1; if (kcn > 15) kcn = 15;
        int r0 = lane >> 2,          q0 = lane & 3;
        int r1 = (lane + 64) >> 2,   q1 = q0;
        int r2 = (lane + 128) >> 2,  q2 = q0;
        int r3 = (lane + 192) >> 2,  q3 = q0;
        float4 g0 = xg[(size_t)(rowbase + r0) * 64 + kcn * 4 + q0];
        float4 g1 = xg[(size_t)(rowbase + r1) * 64 + kcn * 4 + q1];
        float4 g2 = xg[(size_t)(rowbase + r2) * 64 + kcn * 4 + q2];
        float4 g3 = xg[(size_t)(rowbase + r3) * 64 + kcn * 4 + q3];

        #pragma unroll
        for (int j = 0; j < 64; ++j) {
            const float4* wr = reinterpret_cast<const float4*>(
                W1 + (size_t)(obase + j) * 256 + kc * 16);     // uniform -> s_load
            float4 a0 = wr[0], a1 = wr[1], a2 = wr[2], a3 = wr[3];
            acc[j] += x0.x*a0.x + x0.y*a0.y + x0.z*a0.z + x0.w*a0.w
                    + x1.x*a1.x + x1.y*a1.y + x1.z*a1.z + x1.w*a1.w
                    + x2.x*a2.x + x2.y*a2.y + x2.z*a2.z + x2.w*a2.w
                    + x3.x*a3.x + x3.y*a3.y + x3.z*a3.z + x3.w*a3.w;
        }

        // write prefetched chunk (wave-lockstep: all reads above already issued)
        xb[(r0 << 2) + (q0 ^ (r0 & 3))] = g0;
        xb[(r1 << 2) + (q1 ^ (r1 & 3))] = g1;
        xb[(r2 << 2) + (q2 ^ (r2 & 3))] = g2;
        xb[(r3 << 2) + (q3 ^ (r3 & 3))] = g3;
    }

    // ---- epilogue 1: t = tanh(acc) -> ts (swizzled), zero acc ----
    #pragma unroll
    for (int s = 0; s < 16; ++s) {
        float4 tv;
        tv.x = tanhf(acc[4*s+0]); tv.y = tanhf(acc[4*s+1]);
        tv.z = tanhf(acc[4*s+2]); tv.w = tanhf(acc[4*s+3]);
        ts[(lrow << 5) + ((16*h + s) ^ (lane & 7))] = tv;
        acc[4*s+0] = 0.f; acc[4*s+1] = 0.f; acc[4*s+2] = 0.f; acc[4*s+3] = 0.f;
    }
    __syncthreads();

    // ---------------- layer 2: K=128, 8 chunks of 16 floats ----------------
    #pragma unroll 1
    for (int kc = 0; kc < 8; ++kc) {
        float4 t0 = ts[(lrow << 5) + ((kc*4+0) ^ (lane & 7))];
        float4 t1 = ts[(lrow << 5) + ((kc*4+1) ^ (lane & 7))];
        float4 t2 = ts[(lrow << 5) + ((kc*4+2) ^ (lane & 7))];
        float4 t3 = ts[(lrow << 5) + ((kc*4+3) ^ (lane & 7))];
        #pragma unroll
        for (int j = 0; j < 64; ++j) {
            const float4* wr = reinterpret_cast<const float4*>(
                W2 + (size_t)(obase + j) * 128 + kc * 16);     // uniform -> s_load
            float4 a0 = wr[0], a1 = wr[1], a2 = wr[2], a3 = wr[3];
            acc[j] += t0.x*a0.x + t0.y*a0.y + t0.z*a0.z + t0.w*a0.w
                    + t1.x*a1.x + t1.y*a1.y + t1.z*a1.z + t1.w*a1.w
                    + t2.x*a2.x + t2.y*a2.y + t2.z*a2.z + t2.w*a2.w
                    + t3.x*a3.x + t3.y*a3.y + t3.z*a3.z + t3.w*a3.w;
        }
    }

    // ---- epilogue 2: v = tanh(acc); partial z over this out-half ----
    float zp = 0.f;
    #pragma unroll
    for (int j = 0; j < 64; ++j)
        zp += tanhf(acc[j]) * Wout[obase + j];                 // uniform -> s_load

    // xbuf is dead for ALL waves (everyone passed the post-L1 barrier)
    float* zpf = reinterpret_cast<float*>(xbuf);
    zpf[lrow * 2 + h] = zp;
    __syncthreads();

    // ---- tail: z -> analytic collapse (h==0 waves cover all 128 rows) ----
    if (h == 0) {
        float z = zpf[lrow * 2] + zpf[lrow * 2 + 1];
        const float CC = 0.8975979010256552f;  // 2*pi/7
        float a = 0.f;
        #pragma unroll
        for (int k = 0; k < 32; ++k)
            a += sob[k] * sinf(CC * soa[k] * z);
        float m   = expf(fabsf(a));
        float res = 4.f * z * m / (4.f * m + 5.f);
        out[blockIdx.x * 128 + lrow] = (a > 0.f) ? res : ((a < 0.f) ? -res : 0.f);
    }
}

extern "C" void kernel_launch(void* const* d_in, const int* in_sizes, int n_in,
                              void* d_out, int out_size, void* d_ws, size_t ws_size,
                              hipStream_t stream) {
    const float* x    = (const float*)d_in[0];
    const float* W1   = (const float*)d_in[1];
    const float* W2   = (const float*)d_in[2];
    const float* Wout = (const float*)d_in[3];
    const float* soa  = (const float*)d_in[8];
    const float* sob  = (const float*)d_in[9];
    float* outp = (float*)d_out;

    dim3 grid(NROWS / 128);   // 512
    dim3 block(256);
    hipLaunchKernelGGL(fused_mlp3, grid, block, 0, stream,
                       x, W1, W2, Wout, soa, sob, outp);
}

// Round 4
// 88.644 us; speedup vs baseline: 6.4173x; 3.7264x over previous
//
#include <hip/hip_runtime.h>
#include <math.h>

// Analytic collapse (verified R1-R3, absmax 3.9e-3):
//   t = tanh(W1 @ x_n); v = tanh(W2 @ t); z = Wout . v
//   a = sum_h sob[h]*sin(2*pi*soa[h]*z/7);  out = sign(a)*4*z*e^|a|/(4e^|a|+5)
//
// R4: fp32-emulated GEMM via bf16 3-level split (h,m,l; trunc/trunc/RNE) and
// 6 MFMA products (hh,hm,mh,mm,hl,lh) on v_mfma_f32_32x32x16_bf16.
// Transposed form D = W * x^T: D col = data-row n = lane&31 (C/D layout:
// col=lane&31, row=(reg&3)+8(reg>>2)+4(lane>>5)), so t never leaves registers;
// layer-2 B-frags are built with cvt-pack + shfl_xor(32) half swap.
// Weights pre-split into bf16 planes in d_ws by a pre-kernel (L2-resident).

typedef __bf16 bf16x8 __attribute__((ext_vector_type(8)));
typedef float  f32x16 __attribute__((ext_vector_type(16)));
typedef unsigned int u32;
typedef unsigned short u16;

union FRAG { uint4 q; bf16x8 v; };

#define NROWS 65536

// ---- bf16 3-level split: x = h + m + l + O(2^-25 |x|) ----
__device__ __forceinline__ void split3(float x, u32& h, u32& m, u32& l) {
    u32 u = __float_as_uint(x);
    h = u >> 16;
    float hf = __uint_as_float(u & 0xFFFF0000u);
    float r1 = x - hf;                       // exact
    u32 u1 = __float_as_uint(r1);
    m = u1 >> 16;
    float mf = __uint_as_float(u1 & 0xFFFF0000u);
    float r2 = r1 - mf;                      // exact
    u32 u2 = __float_as_uint(r2);
    l = (u2 + 0x7FFFu + ((u2 >> 16) & 1u)) >> 16;   // RNE
}

__device__ __forceinline__ float fast_tanh(float x) {
    float e = __expf(2.f * x);
    return 1.f - 2.f * __builtin_amdgcn_rcpf(e + 1.f);  // inf-safe, ~4e-7 abs err
}

// ================= pre-kernel: split W1, W2 into bf16 planes in d_ws =========
// ws layout (u16 elems): W1 planes h,m,l at 0 / 32768 / 65536  ([128][256])
//                        W2 planes h,m,l at 98304 + {0,16384,32768} ([128][128])
__global__ void presplit(const float* __restrict__ W1,
                         const float* __restrict__ W2,
                         u16* __restrict__ ws)
{
    int i = blockIdx.x * 256 + threadIdx.x;   // grid covers 49152
    u32 h, m, l;
    if (i < 32768) {
        split3(W1[i], h, m, l);
        ws[i] = (u16)h; ws[32768 + i] = (u16)m; ws[65536 + i] = (u16)l;
    } else {
        int j = i - 32768;                    // 0..16383
        split3(W2[j], h, m, l);
        ws[98304 + j] = (u16)h; ws[114688 + j] = (u16)m; ws[131072 + j] = (u16)l;
    }
}

// ================= main kernel ==============================================
// block = 256 thr = 4 waves; block n-tile = 128 data rows; wave n-subtile = 32.
// Each wave computes D[o=0..127][its 32 n] : acc = f32x16[4] (4 o-tiles).
__global__ __launch_bounds__(256, 2)
void fused_mlp4(const float* __restrict__ x,
                const u16*   __restrict__ wsp,
                const float* __restrict__ Wout,
                const float* __restrict__ soa,
                const float* __restrict__ sob,
                float* __restrict__ out)
{
    // LDS: x^T split planes for current K-chunk: [3 levels][128 n][8 slots of 16B]
    __shared__ uint4 pl[3][128 * 8];          // 48 KB

    const int tid  = threadIdx.x;
    const int w    = tid >> 6;
    const int lane = tid & 63;
    const int l31  = lane & 31;
    const int hi   = lane >> 5;
    const int nloc = 32 * w + l31;            // this lane's data-row (local)
    const int n0g  = blockIdx.x * 128;

    const float4* xg4 = reinterpret_cast<const float4*>(x);  // [N][64]

    f32x16 acc[4];
    #pragma unroll
    for (int ot = 0; ot < 4; ++ot) acc[ot] = (f32x16)0.f;

    // =================== layer 1: K=256, 4 chunks of 64 ===================
    #pragma unroll 1
    for (int c = 0; c < 4; ++c) {
        // ---- stage: global x -> 3 bf16 LDS planes (swizzled 16B slots) ----
        #pragma unroll
        for (int it = 0; it < 4; ++it) {
            int p   = tid + it * 256;         // 0..1023 (pairs of f4)
            int row = p >> 3;                 // 0..127
            int kp  = p & 7;                  // 16B slot within chunk
            const float4* sp = xg4 + (size_t)(n0g + row) * 64 + c * 16 + kp * 2;
            float4 a = sp[0], b = sp[1];
            u32 h0,m0,l0,h1,m1,l1;
            uint4 H, M, L;
            split3(a.x,h0,m0,l0); split3(a.y,h1,m1,l1);
            H.x = h0|(h1<<16); M.x = m0|(m1<<16); L.x = l0|(l1<<16);
            split3(a.z,h0,m0,l0); split3(a.w,h1,m1,l1);
            H.y = h0|(h1<<16); M.y = m0|(m1<<16); L.y = l0|(l1<<16);
            split3(b.x,h0,m0,l0); split3(b.y,h1,m1,l1);
            H.z = h0|(h1<<16); M.z = m0|(m1<<16); L.z = l0|(l1<<16);
            split3(b.z,h0,m0,l0); split3(b.w,h1,m1,l1);
            H.w = h0|(h1<<16); M.w = m0|(m1<<16); L.w = l0|(l1<<16);
            int slot = kp ^ (row & 7);
            pl[0][row * 8 + slot] = H;
            pl[1][row * 8 + slot] = M;
            pl[2][row * 8 + slot] = L;
        }
        __syncthreads();

        // ---- compute: 4 K16-steps ----
        #pragma unroll
        for (int s = 0; s < 4; ++s) {
            FRAG Bh, Bm, Bl;
            int slot = (2 * s + hi) ^ (nloc & 7);
            Bh.q = pl[0][nloc * 8 + slot];
            Bm.q = pl[1][nloc * 8 + slot];
            Bl.q = pl[2][nloc * 8 + slot];
            #pragma unroll
            for (int ot = 0; ot < 4; ++ot) {
                size_t e = (size_t)(32 * ot + l31) * 256 + c * 64 + s * 16 + 8 * hi;
                FRAG Ah, Am, Al;
                Ah.q = *reinterpret_cast<const uint4*>(wsp +         e);
                Am.q = *reinterpret_cast<const uint4*>(wsp + 32768 + e);
                Al.q = *reinterpret_cast<const uint4*>(wsp + 65536 + e);
                acc[ot] = __builtin_amdgcn_mfma_f32_32x32x16_bf16(Ah.v, Bh.v, acc[ot], 0,0,0);
                acc[ot] = __builtin_amdgcn_mfma_f32_32x32x16_bf16(Ah.v, Bm.v, acc[ot], 0,0,0);
                acc[ot] = __builtin_amdgcn_mfma_f32_32x32x16_bf16(Am.v, Bh.v, acc[ot], 0,0,0);
                acc[ot] = __builtin_amdgcn_mfma_f32_32x32x16_bf16(Am.v, Bm.v, acc[ot], 0,0,0);
                acc[ot] = __builtin_amdgcn_mfma_f32_32x32x16_bf16(Ah.v, Bl.v, acc[ot], 0,0,0);
                acc[ot] = __builtin_amdgcn_mfma_f32_32x32x16_bf16(Al.v, Bh.v, acc[ot], 0,0,0);
            }
        }
        __syncthreads();
    }

    // ====== t = tanh(D1); build layer-2 B-frags in registers ======
    // D1: lane holds o1 = 32*ft + (reg&3) + 8*(reg>>2) + 4*hi for its n.
    // Layer-2 B-frag (step s): lane needs k=o1 = 16s + 8*hi_lane + j, j=0..7:
    //   lo lane: [own regs 8sub..+3 | partner regs 8sub..+3]      (ft=s>>1, sub=s&1)
    //   hi lane: [partner regs 8sub+4..+7 | own regs 8sub+4..+7]
    FRAG tf[3][8];
    #pragma unroll
    for (int ft = 0; ft < 4; ++ft) {
        #pragma unroll
        for (int sub = 0; sub < 2; ++sub) {
            int s = 2 * ft + sub;
            float tv[8];
            u32 th[8], tm[8], tl[8];
            #pragma unroll
            for (int j = 0; j < 8; ++j) {
                tv[j] = fast_tanh(acc[ft][8 * sub + j]);
                split3(tv[j], th[j], tm[j], tl[j]);
            }
            #pragma unroll
            for (int lv = 0; lv < 3; ++lv) {
                const u32* t_ = (lv == 0) ? th : (lv == 1) ? tm : tl;
                u32 P0 = t_[0] | (t_[1] << 16);
                u32 P1 = t_[2] | (t_[3] << 16);
                u32 Q0 = t_[4] | (t_[5] << 16);
                u32 Q1 = t_[6] | (t_[7] << 16);
                u32 sP0 = (u32)__shfl_xor((int)P0, 32);
                u32 sP1 = (u32)__shfl_xor((int)P1, 32);
                u32 sQ0 = (u32)__shfl_xor((int)Q0, 32);
                u32 sQ1 = (u32)__shfl_xor((int)Q1, 32);
                tf[lv][s].q.x = hi ? sQ0 : P0;
                tf[lv][s].q.y = hi ? sQ1 : P1;
                tf[lv][s].q.z = hi ? Q0 : sP0;
                tf[lv][s].q.w = hi ? Q1 : sP1;
            }
        }
    }

    // =================== layer 2: K=128, 8 K16-steps ===================
    f32x16 acc2[4];
    #pragma unroll
    for (int ot = 0; ot < 4; ++ot) acc2[ot] = (f32x16)0.f;

    #pragma unroll
    for (int s = 0; s < 8; ++s) {
        #pragma unroll
        for (int ot = 0; ot < 4; ++ot) {
            size_t e = 98304 + (size_t)(32 * ot + l31) * 128 + s * 16 + 8 * hi;
            FRAG Ah, Am, Al;
            Ah.q = *reinterpret_cast<const uint4*>(wsp +         e);
            Am.q = *reinterpret_cast<const uint4*>(wsp + 16384 + e);
            Al.q = *reinterpret_cast<const uint4*>(wsp + 32768 + e);
            acc2[ot] = __builtin_amdgcn_mfma_f32_32x32x16_bf16(Ah.v, tf[0][s].v, acc2[ot], 0,0,0);
            acc2[ot] = __builtin_amdgcn_mfma_f32_32x32x16_bf16(Ah.v, tf[1][s].v, acc2[ot], 0,0,0);
            acc2[ot] = __builtin_amdgcn_mfma_f32_32x32x16_bf16(Am.v, tf[0][s].v, acc2[ot], 0,0,0);
            acc2[ot] = __builtin_amdgcn_mfma_f32_32x32x16_bf16(Am.v, tf[1][s].v, acc2[ot], 0,0,0);
            acc2[ot] = __builtin_amdgcn_mfma_f32_32x32x16_bf16(Ah.v, tf[2][s].v, acc2[ot], 0,0,0);
            acc2[ot] = __builtin_amdgcn_mfma_f32_32x32x16_bf16(Al.v, tf[0][s].v, acc2[ot], 0,0,0);
        }
    }

    // ====== epilogue: v = tanh(D2); z = Wout . v ; analytic tail ======
    float zp = 0.f;
    #pragma unroll
    for (int ft = 0; ft < 4; ++ft) {
        #pragma unroll
        for (int rg = 0; rg < 4; ++rg) {
            // o2 = 32ft + 8rg + 4hi + j  (j=0..3) = acc2[ft][4rg+j]
            const float4 wo = *reinterpret_cast<const float4*>(Wout + 32 * ft + 8 * rg + 4 * hi);
            zp += fast_tanh(acc2[ft][4 * rg + 0]) * wo.x
                + fast_tanh(acc2[ft][4 * rg + 1]) * wo.y
                + fast_tanh(acc2[ft][4 * rg + 2]) * wo.z
                + fast_tanh(acc2[ft][4 * rg + 3]) * wo.w;
        }
    }
    float z = zp + __shfl_xor(zp, 32);

    if (lane < 32) {
        const float CC = 0.8975979010256552f;   // 2*pi/7
        float a = 0.f;
        #pragma unroll
        for (int k = 0; k < 32; ++k)
            a += sob[k] * sinf(CC * soa[k] * z);
        float mm  = expf(fabsf(a));
        float res = 4.f * z * mm / (4.f * mm + 5.f);
        out[n0g + 32 * w + lane] = (a > 0.f) ? res : ((a < 0.f) ? -res : 0.f);
    }
}

extern "C" void kernel_launch(void* const* d_in, const int* in_sizes, int n_in,
                              void* d_out, int out_size, void* d_ws, size_t ws_size,
                              hipStream_t stream) {
    const float* x    = (const float*)d_in[0];
    const float* W1   = (const float*)d_in[1];
    const float* W2   = (const float*)d_in[2];
    const float* Wout = (const float*)d_in[3];
    const float* soa  = (const float*)d_in[8];
    const float* sob  = (const float*)d_in[9];
    float* outp = (float*)d_out;
    u16* ws = (u16*)d_ws;   // needs 294912 B; harness scratch is larger

    hipLaunchKernelGGL(presplit, dim3(192), dim3(256), 0, stream, W1, W2, ws);
    hipLaunchKernelGGL(fused_mlp4, dim3(NROWS / 128), dim3(256), 0, stream,
                       x, ws, Wout, soa, sob, outp);
}

// Round 5
// 60.881 us; speedup vs baseline: 9.3438x; 1.4560x over previous
//
#include <hip/hip_runtime.h>
#include <math.h>

// Analytic collapse (verified R1-R4, absmax 3.9e-3):
//   t = tanh(W1 @ x_n); v = tanh(W2 @ t); z = Wout . v
//   a = sum_h sob[h]*sin(2*pi*soa[h]*z/7);  out = sign(a)*4*z*e^|a|/(4e^|a|+5)
//
// R5: same fp32-emulated MFMA scheme as R4 (bf16 3-level split, 6 products,
// v_mfma_f32_32x32x16_bf16, transposed D = W * x^T), with two changes:
//   1. Weights pre-split into FRAGMENT-MAJOR layout: the 64 lanes' 16B
//      A-fragments for each (frag, level) are contiguous (1 KB) -> every
//      A-load is a fully-coalesced global_load_dwordx4 (was 32-line gather).
//   2. x chunk software-prefetched into registers during the MFMA phase.

typedef __bf16 bf16x8 __attribute__((ext_vector_type(8)));
typedef float  f32x16 __attribute__((ext_vector_type(16)));
typedef unsigned int u32;
typedef unsigned short u16;

union FRAG { uint4 q; bf16x8 v; };

#define NROWS 65536

// ---- bf16 3-level split: x = h + m + l + O(2^-25 |x|) ----
__device__ __forceinline__ void split3(float x, u32& h, u32& m, u32& l) {
    u32 u = __float_as_uint(x);
    h = u >> 16;
    float hf = __uint_as_float(u & 0xFFFF0000u);
    float r1 = x - hf;                       // exact
    u32 u1 = __float_as_uint(r1);
    m = u1 >> 16;
    float mf = __uint_as_float(u1 & 0xFFFF0000u);
    float r2 = r1 - mf;                      // exact
    u32 u2 = __float_as_uint(r2);
    l = (u2 + 0x7FFFu + ((u2 >> 16) & 1u)) >> 16;   // RNE
}

__device__ __forceinline__ float fast_tanh(float x) {
    float e = __expf(2.f * x);
    return 1.f - 2.f * __builtin_amdgcn_rcpf(e + 1.f);  // inf-safe, ~4e-7 abs err
}

// ====== pre-kernel: split W1/W2 into fragment-major bf16 planes in d_ws ======
// uint4 units (16B per lane-fragment):
//   L1: frag f = c*16 + s*4 + ot (64 frags), levels at 0 / 4096 / 8192:
//       idx = lvoff + f*64 + lane ; holds W1[(32ot+l31)][c*64+s*16+8hi+{0..7}]
//   L2: frag f2 = s*4 + ot (32 frags), levels at 12288 + {0,2048,4096}:
//       idx = lvoff + f2*64 + lane ; holds W2[(32ot+l31)][s*16+8hi+{0..7}]
__global__ void presplit(const float* __restrict__ W1,
                         const float* __restrict__ W2,
                         u16* __restrict__ ws)
{
    int t = blockIdx.x * 256 + threadIdx.x;   // 0..6143
    const float* src;
    size_t dbase;                              // u16 offset of level-0 dest
    size_t lstep;                              // u16 stride between levels
    if (t < 4096) {
        int f = t >> 6, lane = t & 63;
        int c = f >> 4, s = (f >> 2) & 3, ot = f & 3;
        int l31 = lane & 31, hi = lane >> 5;
        src   = W1 + (size_t)(32 * ot + l31) * 256 + c * 64 + s * 16 + 8 * hi;
        dbase = (size_t)(f * 64 + lane) * 8;
        lstep = 32768;
    } else {
        int t2 = t - 4096;
        int f = t2 >> 6, lane = t2 & 63;
        int s = f >> 2, ot = f & 3;
        int l31 = lane & 31, hi = lane >> 5;
        src   = W2 + (size_t)(32 * ot + l31) * 128 + s * 16 + 8 * hi;
        dbase = 98304 + (size_t)(f * 64 + lane) * 8;
        lstep = 16384;
    }
    u16 H[8], M[8], L[8];
    #pragma unroll
    for (int j = 0; j < 8; ++j) {
        u32 h, m, l;
        split3(src[j], h, m, l);
        H[j] = (u16)h; M[j] = (u16)m; L[j] = (u16)l;
    }
    #pragma unroll
    for (int j = 0; j < 8; ++j) {
        ws[dbase + j]             = H[j];
        ws[dbase + lstep + j]     = M[j];
        ws[dbase + 2 * lstep + j] = L[j];
    }
}

// ================= main kernel ==============================================
// block = 256 thr = 4 waves; block n-tile = 128 rows; wave n-subtile = 32.
__global__ __launch_bounds__(256, 2)
void fused_mlp5(const float* __restrict__ x,
                const u16*   __restrict__ wsp,
                const float* __restrict__ Wout,
                const float* __restrict__ soa,
                const float* __restrict__ sob,
                float* __restrict__ out)
{
    __shared__ uint4 pl[3][128 * 8];          // 48 KB: x^T planes, swizzled 16B slots

    const int tid  = threadIdx.x;
    const int w    = tid >> 6;
    const int lane = tid & 63;
    const int l31  = lane & 31;
    const int hi   = lane >> 5;
    const int nloc = 32 * w + l31;
    const int n0g  = blockIdx.x * 128;

    const float4* xg4 = reinterpret_cast<const float4*>(x);   // [N][64]
    const uint4*  wf  = reinterpret_cast<const uint4*>(wsp);  // fragment-major

    const int srow = tid >> 3;                 // staging row 0..31 (+32/it)
    const int skp  = tid & 7;                  // staging 16B slot pair

    f32x16 acc[4];
    #pragma unroll
    for (int ot = 0; ot < 4; ++ot) acc[ot] = (f32x16)0.f;

    // ---- prologue: load x chunk 0 into registers ----
    float4 gx[8];
    #pragma unroll
    for (int it = 0; it < 4; ++it) {
        const float4* sp = xg4 + (size_t)(n0g + srow + 32 * it) * 64 + skp * 2;
        gx[2 * it]     = sp[0];
        gx[2 * it + 1] = sp[1];
    }

    // =================== layer 1: K=256, 4 chunks of 64 ===================
    #pragma unroll 1
    for (int c = 0; c < 4; ++c) {
        // ---- split gx -> 3 bf16 LDS planes ----
        #pragma unroll
        for (int it = 0; it < 4; ++it) {
            int row = srow + 32 * it;
            float4 a = gx[2 * it], b = gx[2 * it + 1];
            u32 h0,m0,l0,h1,m1,l1;
            uint4 H, M, L;
            split3(a.x,h0,m0,l0); split3(a.y,h1,m1,l1);
            H.x = h0|(h1<<16); M.x = m0|(m1<<16); L.x = l0|(l1<<16);
            split3(a.z,h0,m0,l0); split3(a.w,h1,m1,l1);
            H.y = h0|(h1<<16); M.y = m0|(m1<<16); L.y = l0|(l1<<16);
            split3(b.x,h0,m0,l0); split3(b.y,h1,m1,l1);
            H.z = h0|(h1<<16); M.z = m0|(m1<<16); L.z = l0|(l1<<16);
            split3(b.z,h0,m0,l0); split3(b.w,h1,m1,l1);
            H.w = h0|(h1<<16); M.w = m0|(m1<<16); L.w = l0|(l1<<16);
            int slot = skp ^ (row & 7);
            pl[0][row * 8 + slot] = H;
            pl[1][row * 8 + slot] = M;
            pl[2][row * 8 + slot] = L;
        }
        __syncthreads();

        // ---- prefetch next chunk's x while MFMAs run ----
        if (c < 3) {
            #pragma unroll
            for (int it = 0; it < 4; ++it) {
                const float4* sp = xg4 + (size_t)(n0g + srow + 32 * it) * 64
                                 + (c + 1) * 16 + skp * 2;
                gx[2 * it]     = sp[0];
                gx[2 * it + 1] = sp[1];
            }
        }

        // ---- compute: 4 K16-steps ----
        #pragma unroll
        for (int s = 0; s < 4; ++s) {
            FRAG Bh, Bm, Bl;
            int slot = (2 * s + hi) ^ (nloc & 7);
            Bh.q = pl[0][nloc * 8 + slot];
            Bm.q = pl[1][nloc * 8 + slot];
            Bl.q = pl[2][nloc * 8 + slot];
            #pragma unroll
            for (int ot = 0; ot < 4; ++ot) {
                int fb = (c * 16 + s * 4 + ot) * 64 + lane;   // coalesced frag
                FRAG Ah, Am, Al;
                Ah.q = wf[fb];
                Am.q = wf[4096 + fb];
                Al.q = wf[8192 + fb];
                acc[ot] = __builtin_amdgcn_mfma_f32_32x32x16_bf16(Ah.v, Bh.v, acc[ot], 0,0,0);
                acc[ot] = __builtin_amdgcn_mfma_f32_32x32x16_bf16(Ah.v, Bm.v, acc[ot], 0,0,0);
                acc[ot] = __builtin_amdgcn_mfma_f32_32x32x16_bf16(Am.v, Bh.v, acc[ot], 0,0,0);
                acc[ot] = __builtin_amdgcn_mfma_f32_32x32x16_bf16(Am.v, Bm.v, acc[ot], 0,0,0);
                acc[ot] = __builtin_amdgcn_mfma_f32_32x32x16_bf16(Ah.v, Bl.v, acc[ot], 0,0,0);
                acc[ot] = __builtin_amdgcn_mfma_f32_32x32x16_bf16(Al.v, Bh.v, acc[ot], 0,0,0);
            }
        }
        __syncthreads();
    }

    // ====== t = tanh(D1); build layer-2 B-frags in registers ======
    FRAG tf[3][8];
    #pragma unroll
    for (int ft = 0; ft < 4; ++ft) {
        #pragma unroll
        for (int sub = 0; sub < 2; ++sub) {
            int s = 2 * ft + sub;
            float tv[8];
            u32 th[8], tm[8], tl[8];
            #pragma unroll
            for (int j = 0; j < 8; ++j) {
                tv[j] = fast_tanh(acc[ft][8 * sub + j]);
                split3(tv[j], th[j], tm[j], tl[j]);
            }
            #pragma unroll
            for (int lv = 0; lv < 3; ++lv) {
                const u32* t_ = (lv == 0) ? th : (lv == 1) ? tm : tl;
                u32 P0 = t_[0] | (t_[1] << 16);
                u32 P1 = t_[2] | (t_[3] << 16);
                u32 Q0 = t_[4] | (t_[5] << 16);
                u32 Q1 = t_[6] | (t_[7] << 16);
                u32 sP0 = (u32)__shfl_xor((int)P0, 32);
                u32 sP1 = (u32)__shfl_xor((int)P1, 32);
                u32 sQ0 = (u32)__shfl_xor((int)Q0, 32);
                u32 sQ1 = (u32)__shfl_xor((int)Q1, 32);
                tf[lv][s].q.x = hi ? sQ0 : P0;
                tf[lv][s].q.y = hi ? sQ1 : P1;
                tf[lv][s].q.z = hi ? Q0 : sP0;
                tf[lv][s].q.w = hi ? Q1 : sP1;
            }
        }
    }

    // =================== layer 2: K=128, 8 K16-steps ===================
    f32x16 acc2[4];
    #pragma unroll
    for (int ot = 0; ot < 4; ++ot) acc2[ot] = (f32x16)0.f;

    #pragma unroll
    for (int s = 0; s < 8; ++s) {
        #pragma unroll
        for (int ot = 0; ot < 4; ++ot) {
            int fb = 12288 + (s * 4 + ot) * 64 + lane;        // coalesced frag
            FRAG Ah, Am, Al;
            Ah.q = wf[fb];
            Am.q = wf[fb + 2048];
            Al.q = wf[fb + 4096];
            acc2[ot] = __builtin_amdgcn_mfma_f32_32x32x16_bf16(Ah.v, tf[0][s].v, acc2[ot], 0,0,0);
            acc2[ot] = __builtin_amdgcn_mfma_f32_32x32x16_bf16(Ah.v, tf[1][s].v, acc2[ot], 0,0,0);
            acc2[ot] = __builtin_amdgcn_mfma_f32_32x32x16_bf16(Am.v, tf[0][s].v, acc2[ot], 0,0,0);
            acc2[ot] = __builtin_amdgcn_mfma_f32_32x32x16_bf16(Am.v, tf[1][s].v, acc2[ot], 0,0,0);
            acc2[ot] = __builtin_amdgcn_mfma_f32_32x32x16_bf16(Ah.v, tf[2][s].v, acc2[ot], 0,0,0);
            acc2[ot] = __builtin_amdgcn_mfma_f32_32x32x16_bf16(Al.v, tf[0][s].v, acc2[ot], 0,0,0);
        }
    }

    // ====== epilogue: v = tanh(D2); z = Wout . v ; analytic tail ======
    float zp = 0.f;
    #pragma unroll
    for (int ft = 0; ft < 4; ++ft) {
        #pragma unroll
        for (int rg = 0; rg < 4; ++rg) {
            const float4 wo = *reinterpret_cast<const float4*>(Wout + 32 * ft + 8 * rg + 4 * hi);
            zp += fast_tanh(acc2[ft][4 * rg + 0]) * wo.x
                + fast_tanh(acc2[ft][4 * rg + 1]) * wo.y
                + fast_tanh(acc2[ft][4 * rg + 2]) * wo.z
                + fast_tanh(acc2[ft][4 * rg + 3]) * wo.w;
        }
    }
    float z = zp + __shfl_xor(zp, 32);

    if (lane < 32) {
        const float CC = 0.8975979010256552f;   // 2*pi/7
        float a = 0.f;
        #pragma unroll
        for (int k = 0; k < 32; ++k)
            a += sob[k] * sinf(CC * soa[k] * z);
        float mm  = expf(fabsf(a));
        float res = 4.f * z * mm / (4.f * mm + 5.f);
        out[n0g + 32 * w + lane] = (a > 0.f) ? res : ((a < 0.f) ? -res : 0.f);
    }
}

extern "C" void kernel_launch(void* const* d_in, const int* in_sizes, int n_in,
                              void* d_out, int out_size, void* d_ws, size_t ws_size,
                              hipStream_t stream) {
    const float* x    = (const float*)d_in[0];
    const float* W1   = (const float*)d_in[1];
    const float* W2   = (const float*)d_in[2];
    const float* Wout = (const float*)d_in[3];
    const float* soa  = (const float*)d_in[8];
    const float* sob  = (const float*)d_in[9];
    float* outp = (float*)d_out;
    u16* ws = (u16*)d_ws;   // needs 294912 B

    hipLaunchKernelGGL(presplit, dim3(24), dim3(256), 0, stream, W1, W2, ws);
    hipLaunchKernelGGL(fused_mlp5, dim3(NROWS / 128), dim3(256), 0, stream,
                       x, ws, Wout, soa, sob, outp);
}